// Round 1
// baseline (1711.394 us; speedup 1.0000x reference)
//
#include <hip/hip_runtime.h>
#include <math.h>

#define GH 256
#define GW 256

__device__ __forceinline__ float wsum(float v) {
    #pragma unroll
    for (int m = 32; m >= 1; m >>= 1) v += __shfl_xor(v, m, 64);
    return v;
}

__global__ __launch_bounds__(64) void dphys_kernel(
    const float* __restrict__ z_grid,
    const float* __restrict__ friction,
    const float* __restrict__ controls,
    const float* __restrict__ robot_points,
    const float* __restrict__ x0,
    const float* __restrict__ xd0,
    const float* __restrict__ R0,
    const float* __restrict__ omega0,
    float* __restrict__ out,
    int T)
{
    const int b = blockIdx.x;
    const int lane = threadIdx.x;
    const float* __restrict__ zg = z_grid + (size_t)b * (GH * GW);
    const float* __restrict__ fg = friction + (size_t)b * (GH * GW);
    const float* __restrict__ ct = controls + (size_t)b * (T * 2);
    float* __restrict__ ob = out + (size_t)b * (T * 3);

    // two robot points per lane (N = 128)
    float ppx[2], ppy[2], ppz[2], pmL[2];
    #pragma unroll
    for (int q = 0; q < 2; ++q) {
        int n = lane + q * 64;
        ppx[q] = robot_points[n * 3 + 0];
        ppy[q] = robot_points[n * 3 + 1];
        ppz[q] = robot_points[n * 3 + 2];
        pmL[q] = (ppy[q] < 0.0f) ? 1.0f : 0.0f;
    }

    // inertia tensor: f32 sums (match JAX), adjugate inverse in double
    float sxx = 0.f, syy = 0.f, szz = 0.f, sxy = 0.f, sxz = 0.f, syz = 0.f;
    #pragma unroll
    for (int q = 0; q < 2; ++q) {
        float X = ppx[q], Y = ppy[q], Z = ppz[q];
        sxx += Y * Y + Z * Z;
        syy += X * X + Z * Z;
        szz += X * X + Y * Y;
        sxy += X * Y;
        sxz += X * Z;
        syz += Y * Z;
    }
    const float mp = 0.3125f;  // MASS / N = 40 / 128, exact
    float Ia  = mp * wsum(sxx);
    float Ibb = mp * wsum(syy);
    float Icc = mp * wsum(szz);
    float Idd = -(mp * wsum(sxy));
    float Iee = -(mp * wsum(sxz));
    float Iff = -(mp * wsum(syz));
    {
        // fall through to double inversion below
    }
    double a = Ia, bb = Ibb, c = Icc, d = Idd, e = Iee, f = Iff;
    double C00 = bb * c - f * f, C01 = e * f - d * c, C02 = d * f - bb * e;
    double C11 = a * c - e * e, C12 = d * e - a * f, C22 = a * bb - d * d;
    double idet = 1.0 / (a * C00 + d * C01 + e * C02);
    const float i00 = (float)(C00 * idet), i01 = (float)(C01 * idet), i02 = (float)(C02 * idet);
    const float i11 = (float)(C11 * idet), i12 = (float)(C12 * idet), i22 = (float)(C22 * idet);

    // replicated state in every lane
    float X0 = x0[b * 3 + 0], X1 = x0[b * 3 + 1], X2 = x0[b * 3 + 2];
    float V0 = xd0[b * 3 + 0], V1 = xd0[b * 3 + 1], V2 = xd0[b * 3 + 2];
    float W0 = omega0[b * 3 + 0], W1 = omega0[b * 3 + 1], W2 = omega0[b * 3 + 2];
    float R00 = R0[b * 9 + 0], R01 = R0[b * 9 + 1], R02 = R0[b * 9 + 2];
    float R10 = R0[b * 9 + 3], R11 = R0[b * 9 + 4], R12 = R0[b * 9 + 5];
    float R20 = R0[b * 9 + 6], R21 = R0[b * 9 + 7], R22 = R0[b * 9 + 8];

    for (int t = 0; t < T; ++t) {
        float cv = ct[t * 2 + 0], cw = ct[t * 2 + 1];
        float half = (cw * 0.6f) * 0.5f;      // w * LY / 2, JAX op order
        float vLs = cv - half, vRs = cv + half;
        // thrust = normalized(R[..., 0]) (first column)
        float tn = fmaxf(sqrtf(R00 * R00 + R10 * R10 + R20 * R20), 1e-6f);
        float th0 = R00 / tn, th1 = R10 / tn, th2 = R20 / tn;

        float inc[2], dh_[2], xdn_[2], fr_[2];
        float nx_[2], ny_[2], nz_[2];
        float xp0_[2], xp1_[2], xp2_[2];
        float rl0_[2], rl1_[2], rl2_[2];

        #pragma unroll
        for (int q = 0; q < 2; ++q) {
            // pts = R @ p + x  (einsum nj,bkj->bnk)
            float rx = R00 * ppx[q] + R01 * ppy[q] + R02 * ppz[q];
            float ry = R10 * ppx[q] + R11 * ppy[q] + R12 * ppz[q];
            float rz = R20 * ppx[q] + R21 * ppy[q] + R22 * ppz[q];
            float Px = rx + X0, Py = ry + X1, Pz = rz + X2;
            float l0 = Px - X0, l1 = Py - X1, l2 = Pz - X2;  // pts - x, JAX recomputes
            // xd_pts = xd + omega x rel
            float xp0 = V0 + (W1 * l2 - W2 * l1);
            float xp1 = V1 + (W2 * l0 - W0 * l2);
            float xp2 = V2 + (W0 * l1 - W1 * l0);

            // bilinear coordinates (match JAX constants exactly)
            float u = (Px + 12.8f) / 0.1f;
            u = fminf(fmaxf(u, 0.0f), 254.999f);
            float vv = (Py + 12.8f) / 0.1f;
            vv = fminf(fmaxf(vv, 0.0f), 254.999f);
            int u0 = (int)floorf(u), v0 = (int)floorf(vv);
            float du = u - (float)u0, dv = vv - (float)v0;
            float w00 = (1.0f - du) * (1.0f - dv);
            float w10 = du * (1.0f - dv);
            float w01 = (1.0f - du) * dv;
            float w11 = du * dv;

            int base = u0 * GW + v0;
            float zz = zg[base] * w00 + zg[base + GW] * w10 + zg[base + 1] * w01 + zg[base + GW + 1] * w11;
            float fr = fg[base] * w00 + fg[base + GW] * w10 + fg[base + 1] * w01 + fg[base + GW + 1] * w11;

            // jnp.gradient at the 4 corners: one-sided (un-halved) at edges, /2 then /RES
            float gx[2][2], gy[2][2];
            #pragma unroll
            for (int ii = 0; ii < 2; ++ii) {
                int i = u0 + ii;
                int ipu = (i < GH - 1) ? i + 1 : i;
                int imu = (i > 0) ? i - 1 : i;
                float scu = (ipu - imu == 2) ? 0.5f : 1.0f;
                #pragma unroll
                for (int jj = 0; jj < 2; ++jj) {
                    int j = v0 + jj;
                    int jpv = (j < GW - 1) ? j + 1 : j;
                    int jmv = (j > 0) ? j - 1 : j;
                    float scv = (jpv - jmv == 2) ? 0.5f : 1.0f;
                    gx[ii][jj] = ((zg[ipu * GW + j] - zg[imu * GW + j]) * scu) / 0.1f;
                    gy[ii][jj] = ((zg[i * GW + jpv] - zg[i * GW + jmv]) * scv) / 0.1f;
                }
            }
            float gxs = gx[0][0] * w00 + gx[1][0] * w10 + gx[0][1] * w01 + gx[1][1] * w11;
            float gys = gy[0][0] * w00 + gy[1][0] * w10 + gy[0][1] * w01 + gy[1][1] * w11;

            // nrm = normalized([-gx, -gy, 1])
            float nx = -gxs, ny = -gys, nzc = 1.0f;
            float nn = fmaxf(sqrtf(nx * nx + ny * ny + nzc * nzc), 1e-6f);
            nx /= nn; ny /= nn; nzc /= nn;

            float dh = Pz - zz;
            float ic = 1.0f / (1.0f + expf(10.0f * dh));   // sigmoid(-10*dh)
            float xdn = xp0 * nx + xp1 * ny + xp2 * nzc;

            inc[q] = ic; dh_[q] = dh; xdn_[q] = xdn; fr_[q] = fr;
            nx_[q] = nx; ny_[q] = ny; nz_[q] = nzc;
            xp0_[q] = xp0; xp1_[q] = xp1; xp2_[q] = xp2;
            rl0_[q] = l0; rl1_[q] = l1; rl2_[q] = l2;
        }

        // phase-1 reduction: sum of in_c over all 128 points
        float sic = wsum(inc[0] + inc[1]);

        // phase-2: forces, torques
        float sF0 = 0.f, sF1 = 0.f, sF2 = 0.f, sT0 = 0.f, sT1 = 0.f, sT2 = 0.f;
        #pragma unroll
        for (int q = 0; q < 2; ++q) {
            float mag = -(1000.0f * dh_[q] + 100.0f * xdn_[q]);
            float Fr0 = mag * nx_[q], Fr1 = mag * ny_[q], Fr2 = mag * nz_[q];
            Fr0 = fminf(fmaxf(Fr0 * inc[q] / sic, -392.0f), 392.0f);
            Fr1 = fminf(fmaxf(Fr1 * inc[q] / sic, -392.0f), 392.0f);
            Fr2 = fminf(fmaxf(Fr2 * inc[q] / sic, -392.0f), 392.0f);
            float Nm = sqrtf(Fr0 * Fr0 + Fr1 * Fr1 + Fr2 * Fr2);
            float cmd = pmL[q] * vLs + (1.0f - pmL[q]) * vRs;
            float sl0 = fr_[q] * (cmd * th0 - xp0_[q]);
            float sl1 = fr_[q] * (cmd * th1 - xp1_[q]);
            float sl2 = fr_[q] * (cmd * th2 - xp2_[q]);
            float sdn = sl0 * nx_[q] + sl1 * ny_[q] + sl2 * nz_[q];
            float Ff0 = fminf(fmaxf(Nm * (sl0 - sdn * nx_[q]), -392.0f), 392.0f);
            float Ff1 = fminf(fmaxf(Nm * (sl1 - sdn * ny_[q]), -392.0f), 392.0f);
            float Ff2 = fminf(fmaxf(Nm * (sl2 - sdn * nz_[q]), -392.0f), 392.0f);
            float Fs0 = Fr0 + Ff0, Fs1 = Fr1 + Ff1, Fs2 = Fr2 + Ff2;
            sF0 += Fs0; sF1 += Fs1; sF2 += Fs2;
            sT0 += rl1_[q] * Fs2 - rl2_[q] * Fs1;
            sT1 += rl2_[q] * Fs0 - rl0_[q] * Fs2;
            sT2 += rl0_[q] * Fs1 - rl1_[q] * Fs0;
        }
        sF0 = wsum(sF0); sF1 = wsum(sF1); sF2 = wsum(sF2);
        sT0 = wsum(sT0); sT1 = wsum(sT1); sT2 = wsum(sT2);

        // omega_d = clip(torque @ I_inv^T, +-2) ; I_inv symmetric
        float od0 = fminf(fmaxf(sT0 * i00 + sT1 * i01 + sT2 * i02, -2.0f), 2.0f);
        float od1 = fminf(fmaxf(sT0 * i01 + sT1 * i11 + sT2 * i12, -2.0f), 2.0f);
        float od2 = fminf(fmaxf(sT0 * i02 + sT1 * i12 + sT2 * i22, -2.0f), 2.0f);

        // integrate (replicated in all lanes)
        V0 += (sF0 / 40.0f) * 0.01f;
        V1 += (sF1 / 40.0f) * 0.01f;
        V2 += ((-392.0f + sF2) / 40.0f) * 0.01f;
        X0 += V0 * 0.01f; X1 += V1 * 0.01f; X2 += V2 * 0.01f;
        W0 += od0 * 0.01f; W1 += od1 * 0.01f; W2 += od2 * 0.01f;

        // rot_step: R = R @ (I + K sin(th dt) + K^2 (1 - cos(th dt)))
        float th = sqrtf(W0 * W0 + W1 * W1 + W2 * W2);
        float thc = fmaxf(th, 1e-6f);
        float k0 = W0 / thc, k1 = W1 / thc, k2 = W2 / thc;
        float sn = sinf(th * 0.01f);
        float cs = 1.0f - cosf(th * 0.01f);
        float A00 = 1.0f - (k2 * k2 + k1 * k1) * cs;
        float A01 = -k2 * sn + k0 * k1 * cs;
        float A02 =  k1 * sn + k0 * k2 * cs;
        float A10 =  k2 * sn + k0 * k1 * cs;
        float A11 = 1.0f - (k2 * k2 + k0 * k0) * cs;
        float A12 = -k0 * sn + k1 * k2 * cs;
        float A20 = -k1 * sn + k0 * k2 * cs;
        float A21 =  k0 * sn + k1 * k2 * cs;
        float A22 = 1.0f - (k1 * k1 + k0 * k0) * cs;
        float N00 = R00 * A00 + R01 * A10 + R02 * A20;
        float N01 = R00 * A01 + R01 * A11 + R02 * A21;
        float N02 = R00 * A02 + R01 * A12 + R02 * A22;
        float N10 = R10 * A00 + R11 * A10 + R12 * A20;
        float N11 = R10 * A01 + R11 * A11 + R12 * A21;
        float N12 = R10 * A02 + R11 * A12 + R12 * A22;
        float N20 = R20 * A00 + R21 * A10 + R22 * A20;
        float N21 = R20 * A01 + R21 * A11 + R22 * A21;
        float N22 = R20 * A02 + R21 * A12 + R22 * A22;
        R00 = N00; R01 = N01; R02 = N02;
        R10 = N10; R11 = N11; R12 = N12;
        R20 = N20; R21 = N21; R22 = N22;

        if (lane == 0) {
            ob[t * 3 + 0] = X0;
            ob[t * 3 + 1] = X1;
            ob[t * 3 + 2] = X2;
        }
    }
}

extern "C" void kernel_launch(void* const* d_in, const int* in_sizes, int n_in,
                              void* d_out, int out_size, void* d_ws, size_t ws_size,
                              hipStream_t stream) {
    const float* z_grid       = (const float*)d_in[0];
    const float* friction     = (const float*)d_in[1];
    const float* controls     = (const float*)d_in[2];
    const float* robot_points = (const float*)d_in[3];
    const float* x0           = (const float*)d_in[4];
    const float* xd0          = (const float*)d_in[5];
    const float* R0           = (const float*)d_in[6];
    const float* omega0       = (const float*)d_in[7];
    int B = in_sizes[4] / 3;                 // 64
    int T = in_sizes[2] / (B * 2);           // 500
    dphys_kernel<<<B, 64, 0, stream>>>(z_grid, friction, controls, robot_points,
                                       x0, xd0, R0, omega0, (float*)d_out, T);
}

// Round 2
// 766.251 us; speedup vs baseline: 2.2335x; 2.2335x over previous
//
#include <hip/hip_runtime.h>
#include <math.h>

#define GH 256
#define GW 256

// wave64 sum via DPP (VALU pipe only), result broadcast to all lanes via readlane(63)
__device__ __forceinline__ float wsum_bcast(float v) {
    v += __builtin_bit_cast(float, __builtin_amdgcn_update_dpp(0, __builtin_bit_cast(int, v), 0xB1, 0xF, 0xF, true));  // quad_perm [1,0,3,2]
    v += __builtin_bit_cast(float, __builtin_amdgcn_update_dpp(0, __builtin_bit_cast(int, v), 0x4E, 0xF, 0xF, true));  // quad_perm [2,3,0,1]
    v += __builtin_bit_cast(float, __builtin_amdgcn_update_dpp(0, __builtin_bit_cast(int, v), 0x141, 0xF, 0xF, true)); // row_half_mirror
    v += __builtin_bit_cast(float, __builtin_amdgcn_update_dpp(0, __builtin_bit_cast(int, v), 0x140, 0xF, 0xF, true)); // row_mirror
    v += __builtin_bit_cast(float, __builtin_amdgcn_update_dpp(0, __builtin_bit_cast(int, v), 0x142, 0xA, 0xF, true)); // row_bcast15 -> rows 1,3
    v += __builtin_bit_cast(float, __builtin_amdgcn_update_dpp(0, __builtin_bit_cast(int, v), 0x143, 0xC, 0xF, true)); // row_bcast31 -> rows 2,3
    return __builtin_bit_cast(float, __builtin_amdgcn_readlane(__builtin_bit_cast(int, v), 63));
}

__device__ __forceinline__ float frcp(float x)  { return __builtin_amdgcn_rcpf(x); }   // ~1 ulp
__device__ __forceinline__ float frsq(float x)  { return __builtin_amdgcn_rsqf(x); }   // ~1 ulp
__device__ __forceinline__ float fexp2(float x) { return __builtin_amdgcn_exp2f(x); }

#define INV2PI 0.15915494309189535f

__global__ __launch_bounds__(64) void dphys_kernel(
    const float* __restrict__ z_grid,
    const float* __restrict__ friction,
    const float* __restrict__ controls,
    const float* __restrict__ robot_points,
    const float* __restrict__ x0,
    const float* __restrict__ xd0,
    const float* __restrict__ R0,
    const float* __restrict__ omega0,
    float* __restrict__ out,
    int T)
{
    const int b = blockIdx.x;
    const int lane = threadIdx.x;
    const float* __restrict__ zg = z_grid + (size_t)b * (GH * GW);
    const float* __restrict__ fg = friction + (size_t)b * (GH * GW);
    const float* __restrict__ ct = controls + (size_t)b * (T * 2);
    float* __restrict__ ob = out + (size_t)b * (T * 3);

    // two robot points per lane (N = 128)
    float ppx[2], ppy[2], ppz[2], pmL[2];
    #pragma unroll
    for (int q = 0; q < 2; ++q) {
        int n = lane + q * 64;
        ppx[q] = robot_points[n * 3 + 0];
        ppy[q] = robot_points[n * 3 + 1];
        ppz[q] = robot_points[n * 3 + 2];
        pmL[q] = (ppy[q] < 0.0f) ? 1.0f : 0.0f;
    }

    // inertia tensor: f32 sums (match JAX), adjugate inverse in double (once, off the hot loop)
    float sxx = 0.f, syy = 0.f, szz = 0.f, sxy = 0.f, sxz = 0.f, syz = 0.f;
    #pragma unroll
    for (int q = 0; q < 2; ++q) {
        float X = ppx[q], Y = ppy[q], Z = ppz[q];
        sxx += Y * Y + Z * Z;
        syy += X * X + Z * Z;
        szz += X * X + Y * Y;
        sxy += X * Y;
        sxz += X * Z;
        syz += Y * Z;
    }
    const float mp = 0.3125f;  // MASS / N = 40 / 128, exact
    float Ia  = mp * wsum_bcast(sxx);
    float Ibb = mp * wsum_bcast(syy);
    float Icc = mp * wsum_bcast(szz);
    float Idd = -(mp * wsum_bcast(sxy));
    float Iee = -(mp * wsum_bcast(sxz));
    float Iff = -(mp * wsum_bcast(syz));
    double a = Ia, bb = Ibb, c = Icc, d = Idd, e = Iee, f = Iff;
    double C00 = bb * c - f * f, C01 = e * f - d * c, C02 = d * f - bb * e;
    double C11 = a * c - e * e, C12 = d * e - a * f, C22 = a * bb - d * d;
    double idet = 1.0 / (a * C00 + d * C01 + e * C02);
    const float i00 = (float)(C00 * idet), i01 = (float)(C01 * idet), i02 = (float)(C02 * idet);
    const float i11 = (float)(C11 * idet), i12 = (float)(C12 * idet), i22 = (float)(C22 * idet);

    // replicated state in every lane
    float X0 = x0[b * 3 + 0], X1 = x0[b * 3 + 1], X2 = x0[b * 3 + 2];
    float V0 = xd0[b * 3 + 0], V1 = xd0[b * 3 + 1], V2 = xd0[b * 3 + 2];
    float W0 = omega0[b * 3 + 0], W1 = omega0[b * 3 + 1], W2 = omega0[b * 3 + 2];
    float R00 = R0[b * 9 + 0], R01 = R0[b * 9 + 1], R02 = R0[b * 9 + 2];
    float R10 = R0[b * 9 + 3], R11 = R0[b * 9 + 4], R12 = R0[b * 9 + 5];
    float R20 = R0[b * 9 + 6], R21 = R0[b * 9 + 7], R22 = R0[b * 9 + 8];

    for (int t = 0; t < T; ++t) {
        float cv = ct[t * 2 + 0], cw = ct[t * 2 + 1];
        float half = (cw * 0.6f) * 0.5f;      // w * LY / 2, JAX op order
        float vLs = cv - half, vRs = cv + half;
        // thrust = normalized(R[..., 0]) (first column); norm >= ~1 so the 1e-6 clip never binds
        float rtn = frsq(R00 * R00 + R10 * R10 + R20 * R20);
        float th0 = R00 * rtn, th1 = R10 * rtn, th2 = R20 * rtn;

        float inc[2], dh_[2], xdn_[2], fr_[2];
        float nx_[2], ny_[2], nz_[2];
        float xp0_[2], xp1_[2], xp2_[2];
        float rl0_[2], rl1_[2], rl2_[2];

        #pragma unroll
        for (int q = 0; q < 2; ++q) {
            // pts = R @ p + x  (einsum nj,bkj->bnk)
            float rx = R00 * ppx[q] + R01 * ppy[q] + R02 * ppz[q];
            float ry = R10 * ppx[q] + R11 * ppy[q] + R12 * ppz[q];
            float rz = R20 * ppx[q] + R21 * ppy[q] + R22 * ppz[q];
            float Px = rx + X0, Py = ry + X1, Pz = rz + X2;
            float l0 = Px - X0, l1 = Py - X1, l2 = Pz - X2;  // pts - x, JAX recomputes
            // xd_pts = xd + omega x rel
            float xp0 = V0 + (W1 * l2 - W2 * l1);
            float xp1 = V1 + (W2 * l0 - W0 * l2);
            float xp2 = V2 + (W0 * l1 - W1 * l0);

            // bilinear coordinates ( /RES -> *10, <=1ulp vs divide )
            float u = (Px + 12.8f) * 10.0f;
            u = fminf(fmaxf(u, 0.0f), 254.999f);
            float vv = (Py + 12.8f) * 10.0f;
            vv = fminf(fmaxf(vv, 0.0f), 254.999f);
            int u0 = (int)u, v0 = (int)vv;   // u,vv >= 0 -> trunc == floor
            float du = u - (float)u0, dv = vv - (float)v0;
            float w00 = (1.0f - du) * (1.0f - dv);
            float w10 = du * (1.0f - dv);
            float w01 = (1.0f - du) * dv;
            float w11 = du * dv;

            int base = u0 * GW + v0;
            float zz = zg[base] * w00 + zg[base + GW] * w10 + zg[base + 1] * w01 + zg[base + GW + 1] * w11;
            float fr = fg[base] * w00 + fg[base + GW] * w10 + fg[base + 1] * w01 + fg[base + GW + 1] * w11;

            // jnp.gradient at the 4 corners: one-sided (un-halved) at edges, /2 then /RES (= *10)
            float gx[2][2], gy[2][2];
            #pragma unroll
            for (int ii = 0; ii < 2; ++ii) {
                int i = u0 + ii;
                int ipu = (i < GH - 1) ? i + 1 : i;
                int imu = (i > 0) ? i - 1 : i;
                float scu = (ipu - imu == 2) ? 0.5f : 1.0f;
                #pragma unroll
                for (int jj = 0; jj < 2; ++jj) {
                    int j = v0 + jj;
                    int jpv = (j < GW - 1) ? j + 1 : j;
                    int jmv = (j > 0) ? j - 1 : j;
                    float scv = (jpv - jmv == 2) ? 0.5f : 1.0f;
                    gx[ii][jj] = ((zg[ipu * GW + j] - zg[imu * GW + j]) * scu) * 10.0f;
                    gy[ii][jj] = ((zg[i * GW + jpv] - zg[i * GW + jmv]) * scv) * 10.0f;
                }
            }
            float gxs = gx[0][0] * w00 + gx[1][0] * w10 + gx[0][1] * w01 + gx[1][1] * w11;
            float gys = gy[0][0] * w00 + gy[1][0] * w10 + gy[0][1] * w01 + gy[1][1] * w11;

            // nrm = normalized([-gx, -gy, 1]); norm >= 1 so clip never binds -> rsq
            float rn = frsq(gxs * gxs + gys * gys + 1.0f);
            float nx = -gxs * rn, ny = -gys * rn, nzc = rn;

            float dh = Pz - zz;
            // sigmoid(-10*dh) = 1/(1+exp(10*dh)); exp(10*dh)=exp2(dh*10*log2(e))
            float ex = fexp2(dh * 14.426950408889634f);
            float ic = frcp(1.0f + ex);      // rcp(inf)=0: airborne points OK
            float xdn = xp0 * nx + xp1 * ny + xp2 * nzc;

            inc[q] = ic; dh_[q] = dh; xdn_[q] = xdn; fr_[q] = fr;
            nx_[q] = nx; ny_[q] = ny; nz_[q] = nzc;
            xp0_[q] = xp0; xp1_[q] = xp1; xp2_[q] = xp2;
            rl0_[q] = l0; rl1_[q] = l1; rl2_[q] = l2;
        }

        // phase-1 reduction: sum of in_c over all 128 points (critical path)
        float sic = wsum_bcast(inc[0] + inc[1]);
        float rsic = frcp(sic);

        // phase-2: forces, torques
        float sF0 = 0.f, sF1 = 0.f, sF2 = 0.f, sT0 = 0.f, sT1 = 0.f, sT2 = 0.f;
        #pragma unroll
        for (int q = 0; q < 2; ++q) {
            float mag = -(1000.0f * dh_[q] + 100.0f * xdn_[q]);
            float s = mag * inc[q] * rsic;   // shared scale for all 3 components
            float Fr0 = fminf(fmaxf(s * nx_[q], -392.0f), 392.0f);
            float Fr1 = fminf(fmaxf(s * ny_[q], -392.0f), 392.0f);
            float Fr2 = fminf(fmaxf(s * nz_[q], -392.0f), 392.0f);
            float Nm = __builtin_amdgcn_sqrtf(Fr0 * Fr0 + Fr1 * Fr1 + Fr2 * Fr2);
            float cmd = pmL[q] * vLs + (1.0f - pmL[q]) * vRs;
            float sl0 = fr_[q] * (cmd * th0 - xp0_[q]);
            float sl1 = fr_[q] * (cmd * th1 - xp1_[q]);
            float sl2 = fr_[q] * (cmd * th2 - xp2_[q]);
            float sdn = sl0 * nx_[q] + sl1 * ny_[q] + sl2 * nz_[q];
            float Ff0 = fminf(fmaxf(Nm * (sl0 - sdn * nx_[q]), -392.0f), 392.0f);
            float Ff1 = fminf(fmaxf(Nm * (sl1 - sdn * ny_[q]), -392.0f), 392.0f);
            float Ff2 = fminf(fmaxf(Nm * (sl2 - sdn * nz_[q]), -392.0f), 392.0f);
            float Fs0 = Fr0 + Ff0, Fs1 = Fr1 + Ff1, Fs2 = Fr2 + Ff2;
            sF0 += Fs0; sF1 += Fs1; sF2 += Fs2;
            sT0 += rl1_[q] * Fs2 - rl2_[q] * Fs1;
            sT1 += rl2_[q] * Fs0 - rl0_[q] * Fs2;
            sT2 += rl0_[q] * Fs1 - rl1_[q] * Fs0;
        }
        sF0 = wsum_bcast(sF0); sF1 = wsum_bcast(sF1); sF2 = wsum_bcast(sF2);
        sT0 = wsum_bcast(sT0); sT1 = wsum_bcast(sT1); sT2 = wsum_bcast(sT2);

        // omega_d = clip(torque @ I_inv^T, +-2) ; I_inv symmetric
        float od0 = fminf(fmaxf(sT0 * i00 + sT1 * i01 + sT2 * i02, -2.0f), 2.0f);
        float od1 = fminf(fmaxf(sT0 * i01 + sT1 * i11 + sT2 * i12, -2.0f), 2.0f);
        float od2 = fminf(fmaxf(sT0 * i02 + sT1 * i12 + sT2 * i22, -2.0f), 2.0f);

        // integrate (replicated in all lanes); /MASS -> * (1/40) (<=1ulp)
        V0 += (sF0 * 0.025f) * 0.01f;
        V1 += (sF1 * 0.025f) * 0.01f;
        V2 += ((-392.0f + sF2) * 0.025f) * 0.01f;
        X0 += V0 * 0.01f; X1 += V1 * 0.01f; X2 += V2 * 0.01f;
        W0 += od0 * 0.01f; W1 += od1 * 0.01f; W2 += od2 * 0.01f;

        // rot_step: R = R @ (I + K sin(th dt) + K^2 (1 - cos(th dt)))
        float th = __builtin_amdgcn_sqrtf(W0 * W0 + W1 * W1 + W2 * W2);
        float rthc = frcp(fmaxf(th, 1e-6f));
        float k0 = W0 * rthc, k1 = W1 * rthc, k2 = W2 * rthc;
        float ang = th * 0.01f;
        float sn = __builtin_amdgcn_sinf(ang * INV2PI);
        float cs = 1.0f - __builtin_amdgcn_cosf(ang * INV2PI);
        float A00 = 1.0f - (k2 * k2 + k1 * k1) * cs;
        float A01 = -k2 * sn + k0 * k1 * cs;
        float A02 =  k1 * sn + k0 * k2 * cs;
        float A10 =  k2 * sn + k0 * k1 * cs;
        float A11 = 1.0f - (k2 * k2 + k0 * k0) * cs;
        float A12 = -k0 * sn + k1 * k2 * cs;
        float A20 = -k1 * sn + k0 * k2 * cs;
        float A21 =  k0 * sn + k1 * k2 * cs;
        float A22 = 1.0f - (k1 * k1 + k0 * k0) * cs;
        float N00 = R00 * A00 + R01 * A10 + R02 * A20;
        float N01 = R00 * A01 + R01 * A11 + R02 * A21;
        float N02 = R00 * A02 + R01 * A12 + R02 * A22;
        float N10 = R10 * A00 + R11 * A10 + R12 * A20;
        float N11 = R10 * A01 + R11 * A11 + R12 * A21;
        float N12 = R10 * A02 + R11 * A12 + R12 * A22;
        float N20 = R20 * A00 + R21 * A10 + R22 * A20;
        float N21 = R20 * A01 + R21 * A11 + R22 * A21;
        float N22 = R20 * A02 + R21 * A12 + R22 * A22;
        R00 = N00; R01 = N01; R02 = N02;
        R10 = N10; R11 = N11; R12 = N12;
        R20 = N20; R21 = N21; R22 = N22;

        if (lane == 0) {
            ob[t * 3 + 0] = X0;
            ob[t * 3 + 1] = X1;
            ob[t * 3 + 2] = X2;
        }
    }
}

extern "C" void kernel_launch(void* const* d_in, const int* in_sizes, int n_in,
                              void* d_out, int out_size, void* d_ws, size_t ws_size,
                              hipStream_t stream) {
    const float* z_grid       = (const float*)d_in[0];
    const float* friction     = (const float*)d_in[1];
    const float* controls     = (const float*)d_in[2];
    const float* robot_points = (const float*)d_in[3];
    const float* x0           = (const float*)d_in[4];
    const float* xd0          = (const float*)d_in[5];
    const float* R0           = (const float*)d_in[6];
    const float* omega0       = (const float*)d_in[7];
    int B = in_sizes[4] / 3;                 // 64
    int T = in_sizes[2] / (B * 2);           // 500
    dphys_kernel<<<B, 64, 0, stream>>>(z_grid, friction, controls, robot_points,
                                       x0, xd0, R0, omega0, (float*)d_out, T);
}

// Round 4
// 622.407 us; speedup vs baseline: 2.7496x; 1.2311x over previous
//
#include <hip/hip_runtime.h>
#include <math.h>

#define GH 256
#define GW 256

typedef float f4 __attribute__((ext_vector_type(4), aligned(4)));
typedef float f2 __attribute__((ext_vector_type(2), aligned(4)));

template<int CTRL, int RMASK>
__device__ __forceinline__ float dpp_add(float v) {
    int r = __builtin_amdgcn_update_dpp(0, __builtin_bit_cast(int, v), CTRL, RMASK, 0xF, true);
    return v + __builtin_bit_cast(float, r);
}

// wave64 sum; every lane of the wave gets the total (as a wave-uniform value)
__device__ __forceinline__ float wave_red(float v) {
    v = dpp_add<0xB1, 0xF>(v);   // quad_perm [1,0,3,2]
    v = dpp_add<0x4E, 0xF>(v);   // quad_perm [2,3,0,1]
    v = dpp_add<0x141, 0xF>(v);  // row_half_mirror
    v = dpp_add<0x140, 0xF>(v);  // row_mirror
    v = dpp_add<0x142, 0xA>(v);  // row_bcast15 -> rows 1,3
    v = dpp_add<0x143, 0xC>(v);  // row_bcast31 -> rows 2,3
    return __builtin_bit_cast(float, __builtin_amdgcn_readlane(__builtin_bit_cast(int, v), 63));
}

__device__ __forceinline__ float frcp(float x)  { return __builtin_amdgcn_rcpf(x); }
__device__ __forceinline__ float frsq(float x)  { return __builtin_amdgcn_rsqf(x); }
__device__ __forceinline__ float fexp2(float x) { return __builtin_amdgcn_exp2f(x); }

#define INV2PI 0.15915494309189535f

__global__ __launch_bounds__(128) void dphys_kernel(
    const float* __restrict__ z_grid,
    const float* __restrict__ friction,
    const float* __restrict__ controls,
    const float* __restrict__ robot_points,
    const float* __restrict__ x0,
    const float* __restrict__ xd0,
    const float* __restrict__ R0,
    const float* __restrict__ omega0,
    float* __restrict__ out,
    int T)
{
    const int b = blockIdx.x;
    const int tid = threadIdx.x;      // 0..127 == point index
    const int wv = tid >> 6;          // wave id 0/1
    __shared__ float ldsA[2];         // phase-1 cross-wave partials
    __shared__ float ldsB[12];        // phase-2 / inertia partials

    const float* __restrict__ zg = z_grid + (size_t)b * (GH * GW);
    const float* __restrict__ fg = friction + (size_t)b * (GH * GW);
    const float* __restrict__ ct = controls + (size_t)b * (T * 2);
    float* __restrict__ ob = out + (size_t)b * (T * 3);

    // one robot point per lane (N = 128)
    const float ppx = robot_points[tid * 3 + 0];
    const float ppy = robot_points[tid * 3 + 1];
    const float ppz = robot_points[tid * 3 + 2];

    // inertia tensor: f32 sums (match JAX), adjugate inverse in double (one-time)
    float I6[6];
    I6[0] = ppy * ppy + ppz * ppz;
    I6[1] = ppx * ppx + ppz * ppz;
    I6[2] = ppx * ppx + ppy * ppy;
    I6[3] = ppx * ppy;
    I6[4] = ppx * ppz;
    I6[5] = ppy * ppz;
    #pragma unroll
    for (int k = 0; k < 6; ++k) I6[k] = wave_red(I6[k]);
    if ((tid & 63) == 0) {
        #pragma unroll
        for (int k = 0; k < 6; ++k) ldsB[wv * 6 + k] = I6[k];
    }
    __syncthreads();
    #pragma unroll
    for (int k = 0; k < 6; ++k) I6[k] += ldsB[(wv ^ 1) * 6 + k];
    const float mp = 0.3125f;  // MASS / N exact
    {
        double a = mp * I6[0], bb = mp * I6[1], c = mp * I6[2];
        double d = -(mp * I6[3]), e = -(mp * I6[4]), f = -(mp * I6[5]);
        double C00 = bb * c - f * f, C01 = e * f - d * c, C02 = d * f - bb * e;
        double C11 = a * c - e * e, C12 = d * e - a * f, C22 = a * bb - d * d;
        double idet = 1.0 / (a * C00 + d * C01 + e * C02);
        I6[0] = (float)(C00 * idet); I6[1] = (float)(C11 * idet); I6[2] = (float)(C22 * idet);
        I6[3] = (float)(C01 * idet); I6[4] = (float)(C02 * idet); I6[5] = (float)(C12 * idet);
    }
    const float i00 = I6[0], i11 = I6[1], i22 = I6[2];
    const float i01 = I6[3], i02 = I6[4], i12 = I6[5];

    // replicated state in every lane
    float X0 = x0[b * 3 + 0], X1 = x0[b * 3 + 1], X2 = x0[b * 3 + 2];
    float V0 = xd0[b * 3 + 0], V1 = xd0[b * 3 + 1], V2 = xd0[b * 3 + 2];
    float W0 = omega0[b * 3 + 0], W1 = omega0[b * 3 + 1], W2 = omega0[b * 3 + 2];
    float R00 = R0[b * 9 + 0], R01 = R0[b * 9 + 1], R02 = R0[b * 9 + 2];
    float R10 = R0[b * 9 + 3], R11 = R0[b * 9 + 4], R12 = R0[b * 9 + 5];
    float R20 = R0[b * 9 + 6], R21 = R0[b * 9 + 7], R22 = R0[b * 9 + 8];

    for (int t = 0; t < T; ++t) {
        float cv = ct[t * 2 + 0], cw = ct[t * 2 + 1];
        float half = (cw * 0.6f) * 0.5f;      // w * LY / 2, JAX op order
        float vLs = cv - half, vRs = cv + half;
        // thrust = normalized(R[..., 0]); norm ~1 so the 1e-6 clip never binds
        float rtn = frsq(R00 * R00 + R10 * R10 + R20 * R20);
        float th0 = R00 * rtn, th1 = R10 * rtn, th2 = R20 * rtn;

        // pts = R @ p + x
        float rx = R00 * ppx + R01 * ppy + R02 * ppz;
        float ry = R10 * ppx + R11 * ppy + R12 * ppz;
        float rz = R20 * ppx + R21 * ppy + R22 * ppz;
        float Px = rx + X0, Py = ry + X1, Pz = rz + X2;
        float l0 = Px - X0, l1 = Py - X1, l2 = Pz - X2;
        float xp0 = V0 + (W1 * l2 - W2 * l1);
        float xp1 = V1 + (W2 * l0 - W0 * l2);
        float xp2 = V2 + (W0 * l1 - W1 * l0);

        float u = (Px + 12.8f) * 10.0f;
        u = fminf(fmaxf(u, 0.0f), 254.999f);
        float vvq = (Py + 12.8f) * 10.0f;
        vvq = fminf(fmaxf(vvq, 0.0f), 254.999f);
        int u0 = (int)u, v0 = (int)vvq;
        float du = u - (float)u0, dv = vvq - (float)v0;
        float w00 = (1.0f - du) * (1.0f - dv);
        float w10 = du * (1.0f - dv);
        float w01 = (1.0f - du) * dv;
        float w11 = du * dv;

        float zz, fr, gxs, gys;
        bool interior = (u0 >= 1) & (u0 <= 253) & (v0 >= 1) & (v0 <= 253);
        if (__all(interior)) {
            // 4x4 z patch rows u0-1..u0+2, cols v0-1..v0+2
            int base = (u0 - 1) * GW + (v0 - 1);
            f4 P0 = *(const f4*)(zg + base);
            f4 P1 = *(const f4*)(zg + base + GW);
            f4 P2 = *(const f4*)(zg + base + 2 * GW);
            f4 P3 = *(const f4*)(zg + base + 3 * GW);
            int fb = u0 * GW + v0;
            f2 F0 = *(const f2*)(fg + fb);
            f2 F1 = *(const f2*)(fg + fb + GW);

            zz = P1.y * w00 + P2.y * w10 + P1.z * w01 + P2.z * w11;
            fr = F0.x * w00 + F1.x * w10 + F0.y * w01 + F1.y * w11;
            // central diffs: ((a-b)*0.5)*10 == (a-b)*5 bit-exact (×0.5 exact)
            float gx00 = (P2.y - P0.y) * 5.0f;
            float gx10 = (P3.y - P1.y) * 5.0f;
            float gx01 = (P2.z - P0.z) * 5.0f;
            float gx11 = (P3.z - P1.z) * 5.0f;
            float gy00 = (P1.z - P1.x) * 5.0f;
            float gy10 = (P2.z - P2.x) * 5.0f;
            float gy01 = (P1.w - P1.y) * 5.0f;
            float gy11 = (P2.w - P2.y) * 5.0f;
            gxs = gx00 * w00 + gx10 * w10 + gx01 * w01 + gx11 * w11;
            gys = gy00 * w00 + gy10 * w10 + gy01 * w01 + gy11 * w11;
        } else {
            // exact edge-handling fallback (never taken for in-bounds trajectories)
            int basei = u0 * GW + v0;
            zz = zg[basei] * w00 + zg[basei + GW] * w10 + zg[basei + 1] * w01 + zg[basei + GW + 1] * w11;
            fr = fg[basei] * w00 + fg[basei + GW] * w10 + fg[basei + 1] * w01 + fg[basei + GW + 1] * w11;
            float gx[2][2], gy[2][2];
            #pragma unroll
            for (int ii = 0; ii < 2; ++ii) {
                int i = u0 + ii;
                int ipu = (i < GH - 1) ? i + 1 : i;
                int imu = (i > 0) ? i - 1 : i;
                float scu = (ipu - imu == 2) ? 0.5f : 1.0f;
                #pragma unroll
                for (int jj = 0; jj < 2; ++jj) {
                    int j = v0 + jj;
                    int jpv = (j < GW - 1) ? j + 1 : j;
                    int jmv = (j > 0) ? j - 1 : j;
                    float scv = (jpv - jmv == 2) ? 0.5f : 1.0f;
                    gx[ii][jj] = ((zg[ipu * GW + j] - zg[imu * GW + j]) * scu) * 10.0f;
                    gy[ii][jj] = ((zg[i * GW + jpv] - zg[i * GW + jmv]) * scv) * 10.0f;
                }
            }
            gxs = gx[0][0] * w00 + gx[1][0] * w10 + gx[0][1] * w01 + gx[1][1] * w11;
            gys = gy[0][0] * w00 + gy[1][0] * w10 + gy[0][1] * w01 + gy[1][1] * w11;
        }

        float rn = frsq(gxs * gxs + gys * gys + 1.0f);
        float nx = -gxs * rn, ny = -gys * rn, nzc = rn;

        float dh = Pz - zz;
        float ex = fexp2(dh * 14.426950408889634f);   // exp(10*dh)
        float ic = frcp(1.0f + ex);                    // sigmoid(-10*dh)
        float xdn = xp0 * nx + xp1 * ny + xp2 * nzc;

        // phase-1: sum in_c over 128 points (DPP + cross-wave LDS)
        float wpart = wave_red(ic);
        if ((tid & 63) == 0) ldsA[wv] = wpart;
        __syncthreads();
        float sic = wpart + ldsA[wv ^ 1];
        float rsic = frcp(sic);

        // phase-2: force + torque for this lane's point
        float mag = -(1000.0f * dh + 100.0f * xdn);
        float s = mag * ic * rsic;
        float Fr0 = fminf(fmaxf(s * nx, -392.0f), 392.0f);
        float Fr1 = fminf(fmaxf(s * ny, -392.0f), 392.0f);
        float Fr2 = fminf(fmaxf(s * nzc, -392.0f), 392.0f);
        float Nm = __builtin_amdgcn_sqrtf(Fr0 * Fr0 + Fr1 * Fr1 + Fr2 * Fr2);
        float cmd = (ppy < 0.0f) ? vLs : vRs;
        float sl0 = fr * (cmd * th0 - xp0);
        float sl1 = fr * (cmd * th1 - xp1);
        float sl2 = fr * (cmd * th2 - xp2);
        float sdn = sl0 * nx + sl1 * ny + sl2 * nzc;
        float Ff0 = fminf(fmaxf(Nm * (sl0 - sdn * nx), -392.0f), 392.0f);
        float Ff1 = fminf(fmaxf(Nm * (sl1 - sdn * ny), -392.0f), 392.0f);
        float Ff2 = fminf(fmaxf(Nm * (sl2 - sdn * nzc), -392.0f), 392.0f);
        float S6[6];
        S6[0] = Fr0 + Ff0; S6[1] = Fr1 + Ff1; S6[2] = Fr2 + Ff2;
        S6[3] = l1 * S6[2] - l2 * S6[1];
        S6[4] = l2 * S6[0] - l0 * S6[2];
        S6[5] = l0 * S6[1] - l1 * S6[0];
        #pragma unroll
        for (int k = 0; k < 6; ++k) S6[k] = wave_red(S6[k]);
        if ((tid & 63) == 0) {
            #pragma unroll
            for (int k = 0; k < 6; ++k) ldsB[wv * 6 + k] = S6[k];
        }
        __syncthreads();
        #pragma unroll
        for (int k = 0; k < 6; ++k) S6[k] += ldsB[(wv ^ 1) * 6 + k];

        // omega_d = clip(torque @ I_inv^T, +-2)
        float od0 = fminf(fmaxf(S6[3] * i00 + S6[4] * i01 + S6[5] * i02, -2.0f), 2.0f);
        float od1 = fminf(fmaxf(S6[3] * i01 + S6[4] * i11 + S6[5] * i12, -2.0f), 2.0f);
        float od2 = fminf(fmaxf(S6[3] * i02 + S6[4] * i12 + S6[5] * i22, -2.0f), 2.0f);

        // integrate
        V0 += (S6[0] * 0.025f) * 0.01f;
        V1 += (S6[1] * 0.025f) * 0.01f;
        V2 += ((-392.0f + S6[2]) * 0.025f) * 0.01f;
        X0 += V0 * 0.01f; X1 += V1 * 0.01f; X2 += V2 * 0.01f;
        W0 += od0 * 0.01f; W1 += od1 * 0.01f; W2 += od2 * 0.01f;

        // rot_step
        float th = __builtin_amdgcn_sqrtf(W0 * W0 + W1 * W1 + W2 * W2);
        float rthc = frcp(fmaxf(th, 1e-6f));
        float k0 = W0 * rthc, k1 = W1 * rthc, k2 = W2 * rthc;
        float ang = th * 0.01f;
        float sn = __builtin_amdgcn_sinf(ang * INV2PI);
        float cs = 1.0f - __builtin_amdgcn_cosf(ang * INV2PI);
        float A00 = 1.0f - (k2 * k2 + k1 * k1) * cs;
        float A01 = -k2 * sn + k0 * k1 * cs;
        float A02 =  k1 * sn + k0 * k2 * cs;
        float A10 =  k2 * sn + k0 * k1 * cs;
        float A11 = 1.0f - (k2 * k2 + k0 * k0) * cs;
        float A12 = -k0 * sn + k1 * k2 * cs;
        float A20 = -k1 * sn + k0 * k2 * cs;
        float A21 =  k0 * sn + k1 * k2 * cs;
        float A22 = 1.0f - (k1 * k1 + k0 * k0) * cs;
        float N00 = R00 * A00 + R01 * A10 + R02 * A20;
        float N01 = R00 * A01 + R01 * A11 + R02 * A21;
        float N02 = R00 * A02 + R01 * A12 + R02 * A22;
        float N10 = R10 * A00 + R11 * A10 + R12 * A20;
        float N11 = R10 * A01 + R11 * A11 + R12 * A21;
        float N12 = R10 * A02 + R11 * A12 + R12 * A22;
        float N20 = R20 * A00 + R21 * A10 + R22 * A20;
        float N21 = R20 * A01 + R21 * A11 + R22 * A21;
        float N22 = R20 * A02 + R21 * A12 + R22 * A22;
        R00 = N00; R01 = N01; R02 = N02;
        R10 = N10; R11 = N11; R12 = N12;
        R20 = N20; R21 = N21; R22 = N22;

        if (tid == 0) {
            ob[t * 3 + 0] = X0;
            ob[t * 3 + 1] = X1;
            ob[t * 3 + 2] = X2;
        }
    }
}

extern "C" void kernel_launch(void* const* d_in, const int* in_sizes, int n_in,
                              void* d_out, int out_size, void* d_ws, size_t ws_size,
                              hipStream_t stream) {
    const float* z_grid       = (const float*)d_in[0];
    const float* friction     = (const float*)d_in[1];
    const float* controls     = (const float*)d_in[2];
    const float* robot_points = (const float*)d_in[3];
    const float* x0           = (const float*)d_in[4];
    const float* xd0          = (const float*)d_in[5];
    const float* R0           = (const float*)d_in[6];
    const float* omega0       = (const float*)d_in[7];
    int B = in_sizes[4] / 3;                 // 64
    int T = in_sizes[2] / (B * 2);           // 500
    dphys_kernel<<<B, 128, 0, stream>>>(z_grid, friction, controls, robot_points,
                                        x0, xd0, R0, omega0, (float*)d_out, T);
}

// Round 5
// 578.387 us; speedup vs baseline: 2.9589x; 1.0761x over previous
//
#include <hip/hip_runtime.h>
#include <math.h>

#define GH 256
#define GW 256

typedef float f4 __attribute__((ext_vector_type(4), aligned(4)));
typedef float f2 __attribute__((ext_vector_type(2), aligned(4)));
typedef float f4l __attribute__((ext_vector_type(4)));   // 16B-aligned (LDS)

template<int CTRL, int RMASK>
__device__ __forceinline__ float dpp_add(float v) {
    int r = __builtin_amdgcn_update_dpp(0, __builtin_bit_cast(int, v), CTRL, RMASK, 0xF, true);
    return v + __builtin_bit_cast(float, r);
}
template<int CTRL, int RMASK>
__device__ __forceinline__ float dpp_max(float v) {
    int r = __builtin_amdgcn_update_dpp(0, __builtin_bit_cast(int, v), CTRL, RMASK, 0xF, true);
    return fmaxf(v, __builtin_bit_cast(float, r));
}

// 6-stage wave64 reduction; total valid in lane 63 (row-3 lanes). No readlane.
__device__ __forceinline__ float wave_sum63(float v) {
    v = dpp_add<0xB1, 0xF>(v);   // quad_perm [1,0,3,2]
    v = dpp_add<0x4E, 0xF>(v);   // quad_perm [2,3,0,1]
    v = dpp_add<0x141, 0xF>(v);  // row_half_mirror
    v = dpp_add<0x140, 0xF>(v);  // row_mirror
    v = dpp_add<0x142, 0xA>(v);  // row_bcast15 -> rows 1,3
    v = dpp_add<0x143, 0xC>(v);  // row_bcast31 -> rows 2,3
    return v;
}
__device__ __forceinline__ float wave_max63(float v) {  // v >= 0 (bound_ctrl zeros are safe)
    v = dpp_max<0xB1, 0xF>(v);
    v = dpp_max<0x4E, 0xF>(v);
    v = dpp_max<0x141, 0xF>(v);
    v = dpp_max<0x140, 0xF>(v);
    v = dpp_max<0x142, 0xA>(v);
    v = dpp_max<0x143, 0xC>(v);
    return v;
}

__device__ __forceinline__ float frcp(float x)  { return __builtin_amdgcn_rcpf(x); }
__device__ __forceinline__ float frsq(float x)  { return __builtin_amdgcn_rsqf(x); }
__device__ __forceinline__ float fexp2(float x) { return __builtin_amdgcn_exp2f(x); }

#define INV2PI 0.15915494309189535f

__global__ __launch_bounds__(128) void dphys_kernel(
    const float* __restrict__ z_grid,
    const float* __restrict__ friction,
    const float* __restrict__ controls,
    const float* __restrict__ robot_points,
    const float* __restrict__ x0,
    const float* __restrict__ xd0,
    const float* __restrict__ R0,
    const float* __restrict__ omega0,
    float* __restrict__ out,
    int T)
{
    const int b = blockIdx.x;
    const int tid = threadIdx.x;      // 0..127 == point index
    const int wv = tid >> 6;          // wave id 0/1
    __shared__ f4l ldsX[2][2][2];     // [parity][wave][half] fast-path exchange
    __shared__ f4l ldsY[2][2];        // slow-path / inertia exchange

    const float* __restrict__ zg = z_grid + (size_t)b * (GH * GW);
    const float* __restrict__ fg = friction + (size_t)b * (GH * GW);
    const float* __restrict__ ct = controls + (size_t)b * (T * 2);
    float* __restrict__ ob = out + (size_t)b * (T * 3);

    const float ppx = robot_points[tid * 3 + 0];
    const float ppy = robot_points[tid * 3 + 1];
    const float ppz = robot_points[tid * 3 + 2];

    // inertia tensor (one-time): f32 sums match JAX; adjugate inverse in double
    float I6[6];
    I6[0] = ppy * ppy + ppz * ppz;
    I6[1] = ppx * ppx + ppz * ppz;
    I6[2] = ppx * ppx + ppy * ppy;
    I6[3] = ppx * ppy;
    I6[4] = ppx * ppz;
    I6[5] = ppy * ppz;
    #pragma unroll
    for (int k = 0; k < 6; ++k) I6[k] = wave_sum63(I6[k]);
    if ((tid & 63) == 63) {
        f4l t0; t0.x = I6[0]; t0.y = I6[1]; t0.z = I6[2]; t0.w = I6[3];
        f4l t1; t1.x = I6[4]; t1.y = I6[5]; t1.z = 0.f; t1.w = 0.f;
        ldsY[wv][0] = t0; ldsY[wv][1] = t1;
    }
    __syncthreads();
    {
        f4l a0 = ldsY[0][0], a1 = ldsY[0][1], b0 = ldsY[1][0], b1 = ldsY[1][1];
        I6[0] = a0.x + b0.x; I6[1] = a0.y + b0.y; I6[2] = a0.z + b0.z;
        I6[3] = a0.w + b0.w; I6[4] = a1.x + b1.x; I6[5] = a1.y + b1.y;
    }
    const float mp = 0.3125f;  // MASS/N exact
    {
        double a = mp * I6[0], bb = mp * I6[1], c = mp * I6[2];
        double d = -(mp * I6[3]), e = -(mp * I6[4]), f = -(mp * I6[5]);
        double C00 = bb * c - f * f, C01 = e * f - d * c, C02 = d * f - bb * e;
        double C11 = a * c - e * e, C12 = d * e - a * f, C22 = a * bb - d * d;
        double idet = 1.0 / (a * C00 + d * C01 + e * C02);
        I6[0] = (float)(C00 * idet); I6[1] = (float)(C11 * idet); I6[2] = (float)(C22 * idet);
        I6[3] = (float)(C01 * idet); I6[4] = (float)(C02 * idet); I6[5] = (float)(C12 * idet);
    }
    const float i00 = I6[0], i11 = I6[1], i22 = I6[2];
    const float i01 = I6[3], i02 = I6[4], i12 = I6[5];

    // replicated state
    float X0 = x0[b * 3 + 0], X1 = x0[b * 3 + 1], X2 = x0[b * 3 + 2];
    float V0 = xd0[b * 3 + 0], V1 = xd0[b * 3 + 1], V2 = xd0[b * 3 + 2];
    float W0 = omega0[b * 3 + 0], W1 = omega0[b * 3 + 1], W2 = omega0[b * 3 + 2];
    float R00 = R0[b * 9 + 0], R01 = R0[b * 9 + 1], R02 = R0[b * 9 + 2];
    float R10 = R0[b * 9 + 3], R11 = R0[b * 9 + 4], R12 = R0[b * 9 + 5];
    float R20 = R0[b * 9 + 6], R21 = R0[b * 9 + 7], R22 = R0[b * 9 + 8];

    for (int t = 0; t < T; ++t) {
        const int par = t & 1;
        f2 cc = *(const f2*)(ct + t * 2);
        float cv = cc.x, cw = cc.y;
        float half = (cw * 0.6f) * 0.5f;
        float vLs = cv - half, vRs = cv + half;
        float rtn = frsq(R00 * R00 + R10 * R10 + R20 * R20);
        float th0 = R00 * rtn, th1 = R10 * rtn, th2 = R20 * rtn;

        // pts = R @ p + x
        float rx = R00 * ppx + R01 * ppy + R02 * ppz;
        float ry = R10 * ppx + R11 * ppy + R12 * ppz;
        float rz = R20 * ppx + R21 * ppy + R22 * ppz;
        float Px = rx + X0, Py = ry + X1, Pz = rz + X2;
        float l0 = Px - X0, l1 = Py - X1, l2 = Pz - X2;
        float xp0 = V0 + (W1 * l2 - W2 * l1);
        float xp1 = V1 + (W2 * l0 - W0 * l2);
        float xp2 = V2 + (W0 * l1 - W1 * l0);

        float u = (Px + 12.8f) * 10.0f;
        u = fminf(fmaxf(u, 0.0f), 254.999f);
        float vvq = (Py + 12.8f) * 10.0f;
        vvq = fminf(fmaxf(vvq, 0.0f), 254.999f);
        int u0 = (int)u, v0 = (int)vvq;
        float du = u - (float)u0, dv = vvq - (float)v0;
        float w00 = (1.0f - du) * (1.0f - dv);
        float w10 = du * (1.0f - dv);
        float w01 = (1.0f - du) * dv;
        float w11 = du * dv;

        float zz, fr, gxs, gys;
        bool interior = (u0 >= 1) & (u0 <= 253) & (v0 >= 1) & (v0 <= 253);
        if (__all(interior)) {
            int base = (u0 - 1) * GW + (v0 - 1);
            f4 P0 = *(const f4*)(zg + base);
            f4 P1 = *(const f4*)(zg + base + GW);
            f4 P2 = *(const f4*)(zg + base + 2 * GW);
            f4 P3 = *(const f4*)(zg + base + 3 * GW);
            int fb = u0 * GW + v0;
            f2 F0 = *(const f2*)(fg + fb);
            f2 F1 = *(const f2*)(fg + fb + GW);

            zz = P1.y * w00 + P2.y * w10 + P1.z * w01 + P2.z * w11;
            fr = F0.x * w00 + F1.x * w10 + F0.y * w01 + F1.y * w11;
            float gx00 = (P2.y - P0.y) * 5.0f;
            float gx10 = (P3.y - P1.y) * 5.0f;
            float gx01 = (P2.z - P0.z) * 5.0f;
            float gx11 = (P3.z - P1.z) * 5.0f;
            float gy00 = (P1.z - P1.x) * 5.0f;
            float gy10 = (P2.z - P2.x) * 5.0f;
            float gy01 = (P1.w - P1.y) * 5.0f;
            float gy11 = (P2.w - P2.y) * 5.0f;
            gxs = gx00 * w00 + gx10 * w10 + gx01 * w01 + gx11 * w11;
            gys = gy00 * w00 + gy10 * w10 + gy01 * w01 + gy11 * w11;
        } else {
            int basei = u0 * GW + v0;
            zz = zg[basei] * w00 + zg[basei + GW] * w10 + zg[basei + 1] * w01 + zg[basei + GW + 1] * w11;
            fr = fg[basei] * w00 + fg[basei + GW] * w10 + fg[basei + 1] * w01 + fg[basei + GW + 1] * w11;
            float gx[2][2], gy[2][2];
            #pragma unroll
            for (int ii = 0; ii < 2; ++ii) {
                int i = u0 + ii;
                int ipu = (i < GH - 1) ? i + 1 : i;
                int imu = (i > 0) ? i - 1 : i;
                float scu = (ipu - imu == 2) ? 0.5f : 1.0f;
                #pragma unroll
                for (int jj = 0; jj < 2; ++jj) {
                    int j = v0 + jj;
                    int jpv = (j < GW - 1) ? j + 1 : j;
                    int jmv = (j > 0) ? j - 1 : j;
                    float scv = (jpv - jmv == 2) ? 0.5f : 1.0f;
                    gx[ii][jj] = ((zg[ipu * GW + j] - zg[imu * GW + j]) * scu) * 10.0f;
                    gy[ii][jj] = ((zg[i * GW + jpv] - zg[i * GW + jmv]) * scv) * 10.0f;
                }
            }
            gxs = gx[0][0] * w00 + gx[1][0] * w10 + gx[0][1] * w01 + gx[1][1] * w11;
            gys = gy[0][0] * w00 + gy[1][0] * w10 + gy[0][1] * w01 + gy[1][1] * w11;
        }

        float rn = frsq(gxs * gxs + gys * gys + 1.0f);
        float nx = -gxs * rn, ny = -gys * rn, nzc = rn;

        float dh = Pz - zz;
        float ex = fexp2(dh * 14.426950408889634f);   // exp(10*dh)
        float ic = frcp(1.0f + ex);                    // sigmoid(-10*dh)
        float xdn = xp0 * nx + xp1 * ny + xp2 * nzc;

        // per-lane force pieces (independent of sic)
        float mag = -(1000.0f * dh + 100.0f * xdn);
        float mic = mag * ic;
        float m_abs = fabsf(mic);
        float cmd = (ppy < 0.0f) ? vLs : vRs;
        float sl0 = fr * (cmd * th0 - xp0);
        float sl1 = fr * (cmd * th1 - xp1);
        float sl2 = fr * (cmd * th2 - xp2);
        float sdn = sl0 * nx + sl1 * ny + sl2 * nzc;
        float st0 = sl0 - sdn * nx;
        float st1 = sl1 - sdn * ny;
        float st2 = sl2 - sdn * nzc;
        // linear (unclipped, unnormalized) combined force & torque
        float g0 = mic * nx  + m_abs * st0;
        float g1 = mic * ny  + m_abs * st1;
        float g2 = mic * nzc + m_abs * st2;
        float q0 = l1 * g2 - l2 * g1;
        float q1 = l2 * g0 - l0 * g2;
        float q2 = l0 * g1 - l1 * g0;
        // conservative clip-bind detector: |F_comp| could exceed 392 only if
        // max(1, |st|_max) * |mic| > 391 * (own-wave sic partial <= sic)
        float stm = fmaxf(fmaxf(fabsf(st0), fabsf(st1)), fabsf(st2));
        float worst = fmaxf(stm, 1.0f) * m_abs;

        // 8 pipelined DPP chains, one exchange, one barrier
        float r_ic = wave_sum63(ic);
        float rg0 = wave_sum63(g0), rg1 = wave_sum63(g1), rg2 = wave_sum63(g2);
        float rq0 = wave_sum63(q0), rq1 = wave_sum63(q1), rq2 = wave_sum63(q2);
        float rw  = wave_max63(worst);
        if ((tid & 63) == 63) {
            f4l h0; h0.x = rg0; h0.y = rg1; h0.z = rg2; h0.w = rq0;
            f4l h1; h1.x = rq1; h1.y = rq2; h1.z = r_ic;
            h1.w = (rw > 391.0f * r_ic) ? 1.0f : 0.0f;
            ldsX[par][wv][0] = h0; ldsX[par][wv][1] = h1;
        }
        __syncthreads();
        f4l a0 = ldsX[par][0][0], a1 = ldsX[par][0][1];
        f4l b0 = ldsX[par][1][0], b1 = ldsX[par][1][1];
        float sic  = a1.z + b1.z;
        float bind = a1.w + b1.w;
        float rsic = frcp(sic);
        float FT0, FT1, FT2, TQ0, TQ1, TQ2;
        if (__builtin_amdgcn_readfirstlane(__builtin_bit_cast(int, bind)) == 0) {
            // fast path: no clip binds anywhere -> totals are linear in 1/sic
            FT0 = (a0.x + b0.x) * rsic;
            FT1 = (a0.y + b0.y) * rsic;
            FT2 = (a0.z + b0.z) * rsic;
            TQ0 = (a0.w + b0.w) * rsic;
            TQ1 = (a1.x + b1.x) * rsic;
            TQ2 = (a1.y + b1.y) * rsic;
        } else {
            // exact slow path (rare: impact transients)
            float s = mic * rsic;
            float Fr0 = fminf(fmaxf(s * nx,  -392.0f), 392.0f);
            float Fr1 = fminf(fmaxf(s * ny,  -392.0f), 392.0f);
            float Fr2 = fminf(fmaxf(s * nzc, -392.0f), 392.0f);
            float Nm = __builtin_amdgcn_sqrtf(Fr0 * Fr0 + Fr1 * Fr1 + Fr2 * Fr2);
            float Ff0 = fminf(fmaxf(Nm * st0, -392.0f), 392.0f);
            float Ff1 = fminf(fmaxf(Nm * st1, -392.0f), 392.0f);
            float Ff2 = fminf(fmaxf(Nm * st2, -392.0f), 392.0f);
            float S0 = Fr0 + Ff0, S1 = Fr1 + Ff1, S2 = Fr2 + Ff2;
            float U0 = l1 * S2 - l2 * S1;
            float U1 = l2 * S0 - l0 * S2;
            float U2 = l0 * S1 - l1 * S0;
            S0 = wave_sum63(S0); S1 = wave_sum63(S1); S2 = wave_sum63(S2);
            U0 = wave_sum63(U0); U1 = wave_sum63(U1); U2 = wave_sum63(U2);
            if ((tid & 63) == 63) {
                f4l h0; h0.x = S0; h0.y = S1; h0.z = S2; h0.w = U0;
                f4l h1; h1.x = U1; h1.y = U2; h1.z = 0.f; h1.w = 0.f;
                ldsY[wv][0] = h0; ldsY[wv][1] = h1;
            }
            __syncthreads();
            f4l c0 = ldsY[0][0], c1 = ldsY[0][1], d0 = ldsY[1][0], d1 = ldsY[1][1];
            FT0 = c0.x + d0.x; FT1 = c0.y + d0.y; FT2 = c0.z + d0.z;
            TQ0 = c0.w + d0.w; TQ1 = c1.x + d1.x; TQ2 = c1.y + d1.y;
        }

        // omega_d = clip(torque @ I_inv^T, +-2)
        float od0 = fminf(fmaxf(TQ0 * i00 + TQ1 * i01 + TQ2 * i02, -2.0f), 2.0f);
        float od1 = fminf(fmaxf(TQ0 * i01 + TQ1 * i11 + TQ2 * i12, -2.0f), 2.0f);
        float od2 = fminf(fmaxf(TQ0 * i02 + TQ1 * i12 + TQ2 * i22, -2.0f), 2.0f);

        // integrate
        V0 += (FT0 * 0.025f) * 0.01f;
        V1 += (FT1 * 0.025f) * 0.01f;
        V2 += ((-392.0f + FT2) * 0.025f) * 0.01f;
        X0 += V0 * 0.01f; X1 += V1 * 0.01f; X2 += V2 * 0.01f;
        W0 += od0 * 0.01f; W1 += od1 * 0.01f; W2 += od2 * 0.01f;

        // rot_step
        float th = __builtin_amdgcn_sqrtf(W0 * W0 + W1 * W1 + W2 * W2);
        float rthc = frcp(fmaxf(th, 1e-6f));
        float k0 = W0 * rthc, k1 = W1 * rthc, k2 = W2 * rthc;
        float ang = th * 0.01f;
        float sn = __builtin_amdgcn_sinf(ang * INV2PI);
        float cs = 1.0f - __builtin_amdgcn_cosf(ang * INV2PI);
        float A00 = 1.0f - (k2 * k2 + k1 * k1) * cs;
        float A01 = -k2 * sn + k0 * k1 * cs;
        float A02 =  k1 * sn + k0 * k2 * cs;
        float A10 =  k2 * sn + k0 * k1 * cs;
        float A11 = 1.0f - (k2 * k2 + k0 * k0) * cs;
        float A12 = -k0 * sn + k1 * k2 * cs;
        float A20 = -k1 * sn + k0 * k2 * cs;
        float A21 =  k0 * sn + k1 * k2 * cs;
        float A22 = 1.0f - (k1 * k1 + k0 * k0) * cs;
        float N00 = R00 * A00 + R01 * A10 + R02 * A20;
        float N01 = R00 * A01 + R01 * A11 + R02 * A21;
        float N02 = R00 * A02 + R01 * A12 + R02 * A22;
        float N10 = R10 * A00 + R11 * A10 + R12 * A20;
        float N11 = R10 * A01 + R11 * A11 + R12 * A21;
        float N12 = R10 * A02 + R11 * A12 + R12 * A22;
        float N20 = R20 * A00 + R21 * A10 + R22 * A20;
        float N21 = R20 * A01 + R21 * A11 + R22 * A21;
        float N22 = R20 * A02 + R21 * A12 + R22 * A22;
        R00 = N00; R01 = N01; R02 = N02;
        R10 = N10; R11 = N11; R12 = N12;
        R20 = N20; R21 = N21; R22 = N22;

        if (tid == 0) {
            ob[t * 3 + 0] = X0;
            ob[t * 3 + 1] = X1;
            ob[t * 3 + 2] = X2;
        }
    }
}

extern "C" void kernel_launch(void* const* d_in, const int* in_sizes, int n_in,
                              void* d_out, int out_size, void* d_ws, size_t ws_size,
                              hipStream_t stream) {
    const float* z_grid       = (const float*)d_in[0];
    const float* friction     = (const float*)d_in[1];
    const float* controls     = (const float*)d_in[2];
    const float* robot_points = (const float*)d_in[3];
    const float* x0           = (const float*)d_in[4];
    const float* xd0          = (const float*)d_in[5];
    const float* R0           = (const float*)d_in[6];
    const float* omega0       = (const float*)d_in[7];
    int B = in_sizes[4] / 3;                 // 64
    int T = in_sizes[2] / (B * 2);           // 500
    dphys_kernel<<<B, 128, 0, stream>>>(z_grid, friction, controls, robot_points,
                                        x0, xd0, R0, omega0, (float*)d_out, T);
}